// Round 4
// baseline (173.648 us; speedup 1.0000x reference)
//
#include <hip/hip_runtime.h>

#define DT_C 0.01f
#define WAITVM(n)  asm volatile("s_waitcnt vmcnt(" #n ")" ::: "memory")
#define WAITLGKM0  asm volatile("s_waitcnt lgkmcnt(0)" ::: "memory")

// async global->LDS, 16B/lane; LDS dest = uniform base + lane*16 (linear).
__device__ __forceinline__ void gload_lds16(const float* g, float* l) {
    __builtin_amdgcn_global_load_lds(
        (const __attribute__((address_space(1))) void*)g,
        (__attribute__((address_space(3))) void*)l,
        16, 0, 0);
}

// Per-buffer float offsets (all 16B-aligned)
#define OFF_X   0        // 14 rows x 64 = 896 dw
#define OFF_C   896      // 2304 dw
#define OFF_Q   3200     // 2304 dw
#define OFF_R   5504     // 3136 dw
#define OFF_ST  8640     // 448 dw
#define BUFDW   9088     // 36352 B per buffer
#define OFF_OUT (2*BUFDW)// 448 dw out-staging (single, reused)
#define GPW     8        // groups (of 64 elements) per wave

// Persistent 1-wave blocks, 8 groups each, double-buffered LDS staging with
// counted vmcnt: stage(g+1) stays in flight while computing g (T3/T4).
// 74.5 KB LDS/block -> 2 blocks/CU; all 512 blocks resident.
__global__ __launch_bounds__(64) void eskf_kernel(
    const float* __restrict__ x,      // (14, B)
    const float* __restrict__ state,  // (B, 7)
    const float* __restrict__ cov,    // (B, 36)
    const float* __restrict__ Qm,     // (B, 36)
    const float* __restrict__ Rm,     // (B, 49)
    float* __restrict__ out,          // (B, 7)
    int B)
{
    __shared__ float lds[2 * BUFDW + 448];
    const int lane  = threadIdx.x;
    const int gbase = blockIdx.x * GPW;      // first group index of this wave

    // ---- stage group g into buffer Lb : 37 gload_lds, all linear copies ----
    auto STAGE = [&](int g, float* Lb) {
        const int eb = (gbase + g) * 64;
        {   // x rows 0..13: LDS [row][64]
            const int r0 = lane >> 4;
            const int c0 = (lane & 15) * 4;
            const float* gx = x + (size_t)eb + c0;
            float* lx = Lb + OFF_X;
            gload_lds16(gx + (size_t)(0  + r0) * B, lx +   0 + 4 * lane);
            gload_lds16(gx + (size_t)(4  + r0) * B, lx + 256 + 4 * lane);
            gload_lds16(gx + (size_t)(8  + r0) * B, lx + 512 + 4 * lane);
            if (lane < 32)
                gload_lds16(gx + (size_t)(12 + r0) * B, lx + 768 + 4 * lane);
        }
        const float* gc = cov + (size_t)eb * 36;
        float* lc = Lb + OFF_C;
#pragma unroll
        for (int k = 0; k < 9; ++k)
            gload_lds16(gc + 4 * (k * 64 + lane), lc + 4 * (k * 64 + lane));

        const float* gq = Qm + (size_t)eb * 36;
        float* lq = Lb + OFF_Q;
#pragma unroll
        for (int k = 0; k < 9; ++k)
            gload_lds16(gq + 4 * (k * 64 + lane), lq + 4 * (k * 64 + lane));

        const float* gr = Rm + (size_t)eb * 49;
        float* lr = Lb + OFF_R;
#pragma unroll
        for (int k = 0; k < 12; ++k)
            gload_lds16(gr + 4 * (k * 64 + lane), lr + 4 * (k * 64 + lane));
        if (lane < 16)
            gload_lds16(gr + 4 * (768 + lane), lr + 4 * (768 + lane));

        const float* gs = state + (size_t)eb * 7;
        float* lst = Lb + OFF_ST;
        gload_lds16(gs + 4 * lane, lst + 4 * lane);
        if (lane < 48)
            gload_lds16(gs + 4 * (64 + lane), lst + 4 * (64 + lane));
    };

    // ---- one phase: read buf, (re)stage g+2 into same buf, math, store ----
    auto PHASE = [&](int g, float* Lb, bool dostage) {
        // x rows: stride-1 across lanes, conflict-free
        float meas[7], tw[6];
#pragma unroll
        for (int i = 0; i < 7; ++i) meas[i] = Lb[OFF_X + i * 64 + lane];
#pragma unroll
        for (int i = 0; i < 6; ++i) tw[i]  = Lb[OFF_X + (8 + i) * 64 + lane];

        // P = cov + Q (b128 reads, stride 36 dw)
        float P[36];
        {
            const float4* c4 = (const float4*)(Lb + OFF_C + lane * 36);
            const float4* q4 = (const float4*)(Lb + OFF_Q + lane * 36);
#pragma unroll
            for (int i = 0; i < 9; ++i) {
                float4 a = c4[i], bq = q4[i];
                P[4 * i + 0] = a.x + bq.x;
                P[4 * i + 1] = a.y + bq.y;
                P[4 * i + 2] = a.z + bq.z;
                P[4 * i + 3] = a.w + bq.w;
            }
        }
        // state: stride 7 (odd -> free)
        float st[7];
        {
            const float* ls = Lb + OFF_ST + lane * 7;
#pragma unroll
            for (int i = 0; i < 7; ++i) st[i] = ls[i];
        }
        // S = R: stride 49 (odd -> free)
        float S[7][7];
        {
            const float* lr = Lb + OFF_R + lane * 49;
#pragma unroll
            for (int i = 0; i < 7; ++i)
#pragma unroll
                for (int j = 0; j < 7; ++j) S[i][j] = lr[i * 7 + j];
        }

        // all ds_reads of this buffer complete before DMA may rewrite it
        WAITLGKM0;
        if (dostage) STAGE(g + 2, Lb);

        // ---- predict_state = inject(state, DT*twist) ----
        float ps[7];
        {
            float d0 = 0.5f * DT_C * tw[3], d1 = 0.5f * DT_C * tw[4], d2 = 0.5f * DT_C * tw[5];
            ps[0] = st[0] + DT_C * tw[0];
            ps[1] = st[1] + DT_C * tw[1];
            ps[2] = st[2] + DT_C * tw[2];
            float w = st[3], xx = st[4], yy = st[5], zz = st[6];
            float qw = w - xx * d0 - yy * d1 - zz * d2;
            float qx = w * d0 + xx + yy * d2 - zz * d1;
            float qy = w * d1 - xx * d2 + yy + zz * d0;
            float qz = w * d2 + xx * d1 - yy * d0 + zz;
            float inv = rsqrtf(qw * qw + qx * qx + qy * qy + qz * qz);
            ps[3] = qw * inv; ps[4] = qx * inv; ps[5] = qy * inv; ps[6] = qz * inv;
        }

        // ---- Qd from ORIGINAL state quat ----
        float Qd[4][3];
        {
            float w = st[3], xx = st[4], yy = st[5], zz = st[6];
            Qd[0][0] = -0.5f * xx; Qd[0][1] = -0.5f * yy; Qd[0][2] = -0.5f * zz;
            Qd[1][0] =  0.5f * w;  Qd[1][1] = -0.5f * zz; Qd[1][2] =  0.5f * yy;
            Qd[2][0] =  0.5f * zz; Qd[2][1] =  0.5f * w;  Qd[2][2] = -0.5f * xx;
            Qd[3][0] = -0.5f * yy; Qd[3][1] =  0.5f * xx; Qd[3][2] =  0.5f * w;
        }

        // ---- S = H P H^T + R ----
#pragma unroll
        for (int i = 0; i < 3; ++i)
#pragma unroll
            for (int j = 0; j < 3; ++j) S[i][j] += P[i * 6 + j];

        float T[4][6];
#pragma unroll
        for (int i = 0; i < 4; ++i)
#pragma unroll
            for (int c = 0; c < 6; ++c) {
                float acc = 0.f;
#pragma unroll
                for (int k = 0; k < 3; ++k) acc += Qd[i][k] * P[(3 + k) * 6 + c];
                T[i][c] = acc;
            }
#pragma unroll
        for (int i = 0; i < 4; ++i)
#pragma unroll
            for (int j = 0; j < 3; ++j) S[3 + i][j] += T[i][j];
#pragma unroll
        for (int i = 0; i < 3; ++i)
#pragma unroll
            for (int j = 0; j < 4; ++j) {
                float acc = 0.f;
#pragma unroll
                for (int k = 0; k < 3; ++k) acc += P[i * 6 + 3 + k] * Qd[j][k];
                S[i][3 + j] += acc;
            }
#pragma unroll
        for (int i = 0; i < 4; ++i)
#pragma unroll
            for (int j = 0; j < 4; ++j) {
                float acc = 0.f;
#pragma unroll
                for (int l = 0; l < 3; ++l) acc += T[i][3 + l] * Qd[j][l];
                S[3 + i][3 + j] += acc;
            }

        // ---- innovation ----
        float y[7];
#pragma unroll
        for (int i = 0; i < 7; ++i) y[i] = meas[i] - ps[i];

        // ---- solve S y = innovation (no-pivot LU; S SPD) ----
#pragma unroll
        for (int k = 0; k < 7; ++k) {
            float inv = 1.0f / S[k][k];
#pragma unroll
            for (int i = k + 1; i < 7; ++i) {
                float f = S[i][k] * inv;
#pragma unroll
                for (int j = k + 1; j < 7; ++j) S[i][j] -= f * S[k][j];
                y[i] -= f * y[k];
            }
        }
#pragma unroll
        for (int k = 6; k >= 0; --k) {
            float acc = y[k];
#pragma unroll
            for (int j = k + 1; j < 7; ++j) acc -= S[k][j] * y[j];
            y[k] = acc / S[k][k];
        }

        // ---- error_state = P @ (H^T y) ----
        float z6[6];
        z6[0] = y[0]; z6[1] = y[1]; z6[2] = y[2];
#pragma unroll
        for (int c = 0; c < 3; ++c) {
            float acc = 0.f;
#pragma unroll
            for (int i = 0; i < 4; ++i) acc += Qd[i][c] * y[3 + i];
            z6[3 + c] = acc;
        }
        float es[6];
#pragma unroll
        for (int i = 0; i < 6; ++i) {
            float acc = 0.f;
#pragma unroll
            for (int j = 0; j < 6; ++j) acc += P[i * 6 + j] * z6[j];
            es[i] = acc;
        }

        // ---- new_state = inject(predict_state, error_state) ----
        float o0 = ps[0] + es[0];
        float o1 = ps[1] + es[1];
        float o2 = ps[2] + es[2];
        float d0 = 0.5f * es[3], d1 = 0.5f * es[4], d2 = 0.5f * es[5];
        float w = ps[3], xx = ps[4], yy = ps[5], zz = ps[6];
        float qw = w - xx * d0 - yy * d1 - zz * d2;
        float qx = w * d0 + xx + yy * d2 - zz * d1;
        float qy = w * d1 - xx * d2 + yy + zz * d0;
        float qz = w * d2 + xx * d1 - yy * d0 + zz;
        float inv = rsqrtf(qw * qw + qx * qx + qy * qy + qz * qz);

        // ---- out via LDS redistribution: stride-7 writes -> f4 stores ----
        {
            float* ol = lds + OFF_OUT + lane * 7;
            ol[0] = o0; ol[1] = o1; ol[2] = o2;
            ol[3] = qw * inv; ol[4] = qx * inv; ol[5] = qy * inv; ol[6] = qz * inv;
            WAITLGKM0;
            float4*       og = (float4*)(out + (size_t)(gbase + g) * 64 * 7);
            const float4* lf = (const float4*)(lds + OFF_OUT);
            og[lane] = lf[lane];
            if (lane < 48) og[64 + lane] = lf[64 + lane];
        }
    };

    float* L0 = lds;
    float* L1 = lds + BUFDW;

    STAGE(0, L0);
    STAGE(1, L1);

    for (int p = 0; p < 4; ++p) {
        bool more = (p < 3);
        WAITVM(37);                       // stage(2p) done; stage(2p+1) in flight
        PHASE(2 * p, L0, more);
        if (more) {
            WAITVM(37);                   // stage(2p+1) done; stage(2p+2) in flight
            PHASE(2 * p + 1, L1, true);
        } else {
            WAITVM(4);                    // last group: drain stage(7)
            PHASE(7, L1, false);
        }
    }
}

extern "C" void kernel_launch(void* const* d_in, const int* in_sizes, int n_in,
                              void* d_out, int out_size, void* d_ws, size_t ws_size,
                              hipStream_t stream) {
    const float* x     = (const float*)d_in[0];
    const float* state = (const float*)d_in[1];
    const float* cov   = (const float*)d_in[2];
    const float* Qm    = (const float*)d_in[3];
    const float* Rm    = (const float*)d_in[4];
    float* out = (float*)d_out;
    int B = in_sizes[1] / 7;              // 262144 = 512 blocks * 8 groups * 64
    int grid = B / (GPW * 64);
    eskf_kernel<<<grid, 64, 0, stream>>>(x, state, cov, Qm, Rm, out, B);
}